// Round 12
// baseline (56.625 us; speedup 1.0000x reference)
//
#include <hip/hip_runtime.h>
#include <math.h>

#define N_ROWS 131072
#define U2_OFF 4096   // floats: swT = ws[0..4095] ([256][16]), U2 = ws[4096..4351] (16x16)
#define XSTRIDE 257   // LDS x-row stride: odd -> compute reads 2-way bank aliased (free)
#define ZXST 20       // z-exchange row stride (measured conflict-free in R7/R8)

// ---------------- stage-1 builder: 8-qubit state, 4 amps/lane ----------------
__device__ __forceinline__ void ry8(float v[4], int lane, int bp, float c, float s) {
  if (bp == 0) {
    float n0 = fmaf(s, v[1], c * v[0]);
    float n1 = fmaf(-s, v[0], c * v[1]);
    float n2 = fmaf(s, v[3], c * v[2]);
    float n3 = fmaf(-s, v[2], c * v[3]);
    v[0] = n0; v[1] = n1; v[2] = n2; v[3] = n3;
  } else if (bp == 1) {
    float n0 = fmaf(s, v[2], c * v[0]);
    float n2 = fmaf(-s, v[0], c * v[2]);
    float n1 = fmaf(s, v[3], c * v[1]);
    float n3 = fmaf(-s, v[1], c * v[3]);
    v[0] = n0; v[1] = n1; v[2] = n2; v[3] = n3;
  } else {
    int lm = 1 << (bp - 2);
    float sgn = ((lane >> (bp - 2)) & 1) ? -s : s;
#pragma unroll
    for (int k = 0; k < 4; ++k) {
      float o = __shfl_xor(v[k], lm);
      v[k] = fmaf(sgn, o, c * v[k]);
    }
  }
}

__device__ __forceinline__ void cnot8(float v[4], int lane, int cb, int tb) {
  if (cb >= 2 && tb >= 2) {
    int lm = 1 << (tb - 2);
    bool hc = (lane >> (cb - 2)) & 1;
#pragma unroll
    for (int k = 0; k < 4; ++k) {
      float o = __shfl_xor(v[k], lm);
      v[k] = hc ? o : v[k];
    }
  } else if (cb >= 2) {
    bool hc = (lane >> (cb - 2)) & 1;
    if (tb == 0) {
      float n0 = hc ? v[1] : v[0], n1 = hc ? v[0] : v[1];
      float n2 = hc ? v[3] : v[2], n3 = hc ? v[2] : v[3];
      v[0] = n0; v[1] = n1; v[2] = n2; v[3] = n3;
    } else {
      float n0 = hc ? v[2] : v[0], n2 = hc ? v[0] : v[2];
      float n1 = hc ? v[3] : v[1], n3 = hc ? v[1] : v[3];
      v[0] = n0; v[1] = n1; v[2] = n2; v[3] = n3;
    }
  } else if (tb >= 2) {
    int lm = 1 << (tb - 2);
#pragma unroll
    for (int k = 0; k < 4; ++k) {
      float o = __shfl_xor(v[k], lm);
      if ((k >> cb) & 1) v[k] = o;
    }
  } else {
    if (cb == 0) { float t = v[1]; v[1] = v[3]; v[3] = t; }
    else         { float t = v[2]; v[2] = v[3]; v[3] = t; }
  }
}

// ---------------- stage-2 builder: full 16-dim state in registers ----------------
template <int BP>
__device__ __forceinline__ void ry16t(float* w, float c, float s) {
#pragma unroll
  for (int i = 0; i < 16; ++i) {
    if (((i >> BP) & 1) == 0) {
      const int j = i | (1 << BP);
      float a = w[i], b = w[j];
      w[i] = fmaf(s, b, c * a);
      w[j] = fmaf(-s, a, c * b);
    }
  }
}
__device__ __forceinline__ void ry16(float* w, int bp, float c, float s) {
  switch (bp) {
    case 0: ry16t<0>(w, c, s); break;
    case 1: ry16t<1>(w, c, s); break;
    case 2: ry16t<2>(w, c, s); break;
    default: ry16t<3>(w, c, s); break;
  }
}
template <int CB, int TB>
__device__ __forceinline__ void cnot16t(float* w) {
#pragma unroll
  for (int i = 0; i < 16; ++i) {
    if (((i >> CB) & 1) == 1 && ((i >> TB) & 1) == 0) {
      const int j = i | (1 << TB);
      float t = w[i]; w[i] = w[j]; w[j] = t;
    }
  }
}
__device__ __forceinline__ void cnot16(float* w, int cb, int tb) {
#define CC(a, b) if (cb == a && tb == b) { cnot16t<a, b>(w); return; }
  CC(0,1) CC(0,2) CC(0,3) CC(1,0) CC(1,2) CC(1,3)
  CC(2,0) CC(2,1) CC(2,3) CC(3,0) CC(3,1) CC(3,2)
#undef CC
}

__global__ void build_states_kernel(const float* __restrict__ thc,
                                    const float* __restrict__ th2,
                                    float* __restrict__ ws) {
  const int blk = blockIdx.x;
  const int lane = threadIdx.x;  // 64 threads
  if (blk < 16) {
    const float* th = thc + blk * 72;
    float v[4] = {0.f, 0.f, 0.f, 0.f};
    if (lane == 0) v[0] = 1.f;
    int p = 0;
    for (int m = 0; m < 8; ++m) {
#pragma unroll
      for (int q = 0; q < 8; ++q) {
        float a = 0.5f * th[p + q];
        ry8(v, lane, 7 - q, __cosf(a), __sinf(a));
      }
      p += 8;
#pragma unroll
      for (int q = 0; q < 8; ++q) {
        int tgt = (m % 2 == 0) ? ((q + 1) & 7) : ((q + 7) & 7);
        cnot8(v, lane, 7 - q, 7 - tgt);
      }
    }
#pragma unroll
    for (int q = 0; q < 8; ++q) {
      float a = 0.5f * th[p + q];
      ry8(v, lane, 7 - q, __cosf(a), __sinf(a));
    }
    // TRANSPOSED store: swT[k][c], k = 4*lane + kk, c = blk
#pragma unroll
    for (int kk = 0; kk < 4; ++kk) ws[(4 * lane + kk) * 16 + blk] = v[kk];
  } else {
    float w[16];
#pragma unroll
    for (int j = 0; j < 16; ++j) w[j] = (j == lane) ? 1.f : 0.f;
    int p = 0;
    for (int m = 0; m < 8; ++m) {
#pragma unroll
      for (int q = 0; q < 4; ++q) {
        float a = 0.5f * th2[p + q];
        ry16(w, 3 - q, __cosf(a), __sinf(a));
      }
      p += 4;
#pragma unroll
      for (int q = 0; q < 4; ++q) {
        int tgt = (m % 2 == 0) ? ((q + 1) & 3) : ((q + 3) & 3);
        cnot16(w, 3 - q, 3 - tgt);
      }
    }
#pragma unroll
    for (int q = 0; q < 4; ++q) {
      float a = 0.5f * th2[p + q];
      ry16(w, 3 - q, __cosf(a), __sinf(a));
    }
    if (lane < 16) {
      float* u2 = ws + U2_OFF;
#pragma unroll
      for (int j = 0; j < 16; ++j) u2[lane * 16 + j] = w[j];
    }
  }
}

__device__ __forceinline__ float silu_g(float z) {
  float v = z / (1.f + __expf(-z));
  return isfinite(v) ? v : 0.f;
}

// async global -> LDS, 4 B per lane (wave-uniform LDS base + lane*4;
// global src is per-lane). One inst = 256 B CONTIGUOUS global.
__device__ __forceinline__ void stage4(const float* g, float* l) {
  __builtin_amdgcn_global_load_lds(
      (const __attribute__((address_space(1))) void*)g,
      (__attribute__((address_space(3))) void*)l, 4, 0, 0);
}

// 16 FMAs: per-lane x element * wave-uniform swT row (s_load -> SGPR operand)
#define FMA16A(zz, xe, sp)                                                     \
  {                                                                            \
    const float xe_ = (xe);                                                    \
    const float* __restrict__ s_ = (sp);                                       \
    _Pragma("unroll") for (int c = 0; c < 16; ++c)                             \
        zz[c] = fmaf(xe_, s_[c], zz[c]);                                       \
  }

// ---------------- main kernel: PAGE-SEQUENTIAL staging ----------------
// Block = 256 thr = 4 waves, ONE 64-row tile (64 KB LDS, 2 blocks/CU; the
// co-resident block's compute hides this block's stage latency).
// Staging: wave w stages rows 16w..16w+15, each row via 4 width-4
// global_load_lds insts of 256 B CONTIGUOUS global -> per HBM page (1 row =
// 1 KB) all 4 requests arrive back-to-back = page-sequential stream, unlike
// all prior k-sliced kernels (R10 diag: 2.8 TB/s ceiling from page misses).
// Compute: lane owns row `lane`, wave owns k-quarter -> sw via wave-uniform
// s_load -> free SGPR operands. XSTRIDE=257 (odd) -> lane-indexed row reads
// land on banks (lane + 4j) mod 32 = 2-way aliased = free (b32 reads).
// z-exchange via LDS (aliased over xs); wave 0 runs the per-lane epilogue
// (normalizations folded out: U2 orthogonal, final P-norm scale-invariant).
__global__ __launch_bounds__(256, 2) void hadamard_main_kernel(
    const float* __restrict__ x, const float* __restrict__ ws,
    float* __restrict__ out) {
  __shared__ __align__(16) float xs[64 * XSTRIDE];  // 65.8 KB

  const int t = threadIdx.x;
  const int lane = t & 63;
  const int w = __builtin_amdgcn_readfirstlane(t >> 6);  // wave id = k-quarter
  const int rb = blockIdx.x * 64;

  const float* __restrict__ swT = ws;  // [256][16]

  // ---- stage 16 rows (this wave's share), page-sequential ----
  {
    const float* gbase = x + (size_t)(rb + 16 * w) * 256 + lane;
    float* lbase = xs + (16 * w) * XSTRIDE;
#pragma unroll
    for (int i = 0; i < 16; ++i) {
#pragma unroll
      for (int s = 0; s < 4; ++s) {
        stage4(gbase + (size_t)i * 256 + s * 64, lbase + i * XSTRIDE + s * 64);
      }
    }
  }
  __syncthreads();  // drains this wave's vmcnt; all 64 rows visible

  // ---- compute: lane = row, k in [64w, 64w+64) ----
  float z[16];
#pragma unroll
  for (int c = 0; c < 16; ++c) z[c] = 0.f;

  {
    const float* __restrict__ xrow = xs + lane * XSTRIDE + 64 * w;
    const float* __restrict__ sq = swT + (size_t)(64 * w) * 16;
#pragma unroll 4
    for (int kb = 0; kb < 16; ++kb) {
      const float x0 = xrow[4 * kb + 0];
      const float x1 = xrow[4 * kb + 1];
      const float x2 = xrow[4 * kb + 2];
      const float x3 = xrow[4 * kb + 3];
      const float* __restrict__ sb = sq + (size_t)(4 * kb) * 16;
      FMA16A(z, x0, sb + 0)
      FMA16A(z, x1, sb + 16)
      FMA16A(z, x2, sb + 32)
      FMA16A(z, x3, sb + 48)
    }
  }

  __syncthreads();  // xs fully consumed; safe to alias as z-exchange

  // ---- exchange k-quarter partials: zx[4][64][ZXST] aliased over xs ----
  float* zx = xs;
  {
    float4* zp = (float4*)&zx[((size_t)w * 64 + lane) * ZXST];
    zp[0] = make_float4(z[0], z[1], z[2], z[3]);
    zp[1] = make_float4(z[4], z[5], z[6], z[7]);
    zp[2] = make_float4(z[8], z[9], z[10], z[11]);
    zp[3] = make_float4(z[12], z[13], z[14], z[15]);
  }
  __syncthreads();

  if (w == 0) {
    float zf[16];
#pragma unroll
    for (int c = 0; c < 16; ++c) zf[c] = 0.f;
#pragma unroll
    for (int p = 0; p < 4; ++p) {
      const float4* zp = (const float4*)&zx[((size_t)p * 64 + lane) * ZXST];
      const float4 a0 = zp[0], a1 = zp[1], a2 = zp[2], a3 = zp[3];
      zf[0] += a0.x;  zf[1] += a0.y;  zf[2] += a0.z;  zf[3] += a0.w;
      zf[4] += a1.x;  zf[5] += a1.y;  zf[6] += a1.z;  zf[7] += a1.w;
      zf[8] += a2.x;  zf[9] += a2.y;  zf[10] += a2.z; zf[11] += a2.w;
      zf[12] += a3.x; zf[13] += a3.y; zf[14] += a3.z; zf[15] += a3.w;
    }

    // ---------------- per-lane epilogue (row = rb + lane) ----------------
    float f[16];
#pragma unroll
    for (int c = 0; c < 16; ++c) f[c] = silu_g(zf[c]);

    // T = f @ U2 (unnormalized; U2 orthogonal => scales cancel in P)
    const float* __restrict__ u2 = ws + U2_OFF;
    float T[16];
#pragma unroll
    for (int j = 0; j < 16; ++j) T[j] = 0.f;
#pragma unroll
    for (int c = 0; c < 16; ++c) {
      const float fc = f[c];
#pragma unroll
      for (int j = 0; j < 16; ++j) T[j] = fmaf(fc, u2[c * 16 + j], T[j]);
    }

    // e[t] = T[t]^2 + T[t+8]^2 ; P = e / sum(e)
    float e[8], es = 0.f;
#pragma unroll
    for (int tt = 0; tt < 8; ++tt) {
      e[tt] = fmaf(T[tt], T[tt], T[tt + 8] * T[tt + 8]);
      es += e[tt];
    }
    const float rinv = 1.f / fmaxf(es, 1e-35f);

    float P[8], lp[8];
#pragma unroll
    for (int tt = 0; tt < 8; ++tt) {
      P[tt] = e[tt] * rinv;
      lp[tt] = __logf(fmaxf(P[tt], 1e-12f));
    }

    const int row = rb + lane;
    float4* o0 = (float4*)(out + (size_t)row * 8);
    o0[0] = make_float4(lp[0], lp[1], lp[2], lp[3]);
    o0[1] = make_float4(lp[4], lp[5], lp[6], lp[7]);
    float4* o1 = (float4*)(out + (size_t)N_ROWS * 8 + (size_t)row * 8);
    o1[0] = make_float4(P[0], P[1], P[2], P[3]);
    o1[1] = make_float4(P[4], P[5], P[6], P[7]);
  }
}

extern "C" void kernel_launch(void* const* d_in, const int* in_sizes, int n_in,
                              void* d_out, int out_size, void* d_ws, size_t ws_size,
                              hipStream_t stream) {
  const float* x = (const float*)d_in[0];
  const float* thc = (const float*)d_in[1];
  const float* th2 = (const float*)d_in[2];
  float* out = (float*)d_out;
  float* ws = (float*)d_ws;

  build_states_kernel<<<17, 64, 0, stream>>>(thc, th2, ws);
  hadamard_main_kernel<<<N_ROWS / 64, 256, 0, stream>>>(x, ws, out);
}